// Round 6
// baseline (196.837 us; speedup 1.0000x reference)
//
#include <hip/hip_runtime.h>
#include <math.h>

#define NB 128   // batch
#define ND 1024  // embed dim
#define NS 14    // sum of K_range
#define NDH 128  // head dim

typedef float f32x4 __attribute__((ext_vector_type(4)));
typedef short bf16x8 __attribute__((ext_vector_type(8)));   // 8 bf16 in 4 VGPRs
typedef unsigned int u32x4 __attribute__((ext_vector_type(4)));

__device__ __forceinline__ unsigned short f2bf(float v) {   // RNE, finite inputs
  unsigned int u = __builtin_bit_cast(unsigned int, v);
  return (unsigned short)((u + 0x7FFFu + ((u >> 16) & 1u)) >> 16);
}
__device__ __forceinline__ float bf2f(unsigned short u) {
  return __builtin_bit_cast(float, (unsigned int)u << 16);
}

// 8 fp32 -> bf16x8 via v_cvt_pk_bf16_f32 (gfx950, T12 primitive)
__device__ __forceinline__ bf16x8 pack_bv(float4 w0, float4 w1) {
  unsigned int u0, u1, u2, u3;
  asm("v_cvt_pk_bf16_f32 %0, %1, %2" : "=v"(u0) : "v"(w0.x), "v"(w0.y));
  asm("v_cvt_pk_bf16_f32 %0, %1, %2" : "=v"(u1) : "v"(w0.z), "v"(w0.w));
  asm("v_cvt_pk_bf16_f32 %0, %1, %2" : "=v"(u2) : "v"(w1.x), "v"(w1.y));
  asm("v_cvt_pk_bf16_f32 %0, %1, %2" : "=v"(u3) : "v"(w1.z), "v"(w1.w));
  u32x4 u = {u0, u1, u2, u3};
  return __builtin_bit_cast(bf16x8, u);
}

// s in [0,14) -> group g in [0,4), k within group
__device__ __forceinline__ void s_decomp(int s, int& g, int& k) {
  if (s < 2)      { g = 0; k = s; }
  else if (s < 5) { g = 1; k = s - 2; }
  else if (s < 9) { g = 2; k = s - 5; }
  else            { g = 3; k = s - 9; }
}
__device__ __forceinline__ const float* grp_ptr(int g, const float* p2, const float* p3,
                                                const float* p4, const float* p5) {
  return g == 0 ? p2 : g == 1 ? p3 : g == 2 ? p4 : p5;
}
__device__ __forceinline__ int grp_base(int g) { return g == 0 ? 0 : g == 1 ? 16 : g == 2 ? 40 : 72; }
__device__ __forceinline__ int grp_k(int g) { return g + 2; }

// ---------------- K1: fused. blocks 0..111 = LayerNorm rows -> hbf2 frag layout; 112..239 = assign ----------------
// hbf2 elem index: c*114688 + ((kblk*7 + m)*64 + q*16 + r16)*8 + e
//   holds H[row = m*16+r16][k = kblk*32 + q*8 + e]  (A-fragment order for 16x16x32 bf16)
__global__ __launch_bounds__(256) void k_assign_ln(
    const float* __restrict__ x,
    const float* __restrict__ p2, const float* __restrict__ p3,
    const float* __restrict__ p4, const float* __restrict__ p5,
    const float* __restrict__ ln_g, const float* __restrict__ ln_b,
    unsigned short* __restrict__ hbf2, float* __restrict__ pall,
    int* __restrict__ cls, int* __restrict__ rows_g, float* __restrict__ minv)
{
  int bid = blockIdx.x, t = threadIdx.x;
  __shared__ __align__(16) float xs[ND];
  float4* xs4 = (float4*)xs;
  if (bid < 112) {
    int r = bid;
    const float* pp; int idx;
    if (r < 16)      { pp = p2; idx = r; }
    else if (r < 40) { pp = p3; idx = r - 16; }
    else if (r < 72) { pp = p4; idx = r - 40; }
    else             { pp = p5; idx = r - 72; }
    const float4* row4 = (const float4*)(pp + (size_t)idx * ND);
    float4 v = row4[t];
    xs4[t] = v;
    float s1 = v.x + v.y + v.z + v.w;
    float s2 = v.x * v.x + v.y * v.y + v.z * v.z + v.w * v.w;
    __shared__ float ra[256], rb[256];
    ra[t] = s1; rb[t] = s2; __syncthreads();
    for (int o = 128; o > 0; o >>= 1) { if (t < o) { ra[t] += ra[t + o]; rb[t] += rb[t + o]; } __syncthreads(); }
    __shared__ float mu, rstd;
    if (t == 0) {
      float m = ra[0] * (1.f / 1024.f);
      float var = rb[0] * (1.f / 1024.f) - m * m;
      mu = m; rstd = rsqrtf(var + 1e-5f);
    }
    __syncthreads();
    ((float4*)(pall + (size_t)r * ND))[t] = xs4[t];
    float4 xv = xs4[t];
    float nx = (xv.x - mu) * rstd, ny = (xv.y - mu) * rstd,
          nz = (xv.z - mu) * rstd, nw = (xv.w - mu) * rstd;
    // fragment-layout target index for d0 = t*4
    int d0 = t * 4;
    int m = r >> 4, rr = r & 15;
    int kblk = d0 >> 5, qq = (d0 >> 3) & 3, e0 = d0 & 7;   // e0 in {0,4}
    size_t fidx = (((size_t)kblk * 7 + m) * 64 + qq * 16 + rr) * 8 + e0;
#pragma unroll
    for (int c = 0; c < 8; ++c) {
      float4 g = ((const float4*)(ln_g + (size_t)c * ND))[t];
      float4 bb = ((const float4*)(ln_b + (size_t)c * ND))[t];
      ushort4 u;
      u.x = f2bf(nx * g.x + bb.x); u.y = f2bf(ny * g.y + bb.y);
      u.z = f2bf(nz * g.z + bb.z); u.w = f2bf(nw * g.w + bb.w);
      *(ushort4*)&hbf2[(size_t)c * 114688 + fidx] = u;
    }
  } else {
    int b = bid - 112;
    __shared__ float d2s[112];
    __shared__ int cls_s[4];
    const float4* xg4 = (const float4*)(x + (size_t)b * ND);
    xs4[t] = xg4[t];
    __syncthreads();
    if (t < 112) {
      const float* pp; int idx;
      if (t < 16)      { pp = p2; idx = t; }
      else if (t < 40) { pp = p3; idx = t - 16; }
      else if (t < 72) { pp = p4; idx = t - 40; }
      else             { pp = p5; idx = t - 72; }
      const float4* pr4 = (const float4*)(pp + (size_t)idx * ND);
      float acc = 0.f;
#pragma unroll 8
      for (int d = 0; d < 256; ++d) {
        float4 a = xs4[d], p = pr4[d];
        float dx = a.x - p.x, dy = a.y - p.y, dz = a.z - p.z, dw = a.w - p.w;
        acc += dx * dx + dy * dy + dz * dz + dw * dw;
      }
      d2s[t] = acc;
    }
    __syncthreads();
    if (t < 4) {
      int base = grp_base(t), kg = grp_k(t), cnt = 8 * kg;
      float mv = d2s[base]; int mi = 0;
      for (int j = 1; j < cnt; ++j) { float v = d2s[base + j]; if (v < mv) { mv = v; mi = j; } }
      int c = mi / kg;
      cls[b * 4 + t] = c; cls_s[t] = c;
      minv[b * 4 + t] = mv;
    }
    __syncthreads();
    if (t < NS) {
      int g, k; s_decomp(t, g, k);
      rows_g[b * NS + t] = grp_base(g) + cls_s[g] * grp_k(g) + k;
    }
  }
}

// ---------------- K1b: single block -- counts/ccnt/order, repr sum, zero scalars ----------------
__global__ __launch_bounds__(128) void k_prep(
    const int* __restrict__ cls, const float* __restrict__ minv,
    int* __restrict__ counts, int* __restrict__ ccnt, int* __restrict__ order,
    float* __restrict__ scal)
{
  __shared__ int cnt_s[32];
  __shared__ int cc_s[8];
  __shared__ float red[128];
  int t = threadIdx.x;
  if (t < 32) cnt_s[t] = 0;
  if (t < 8) cc_s[t] = 0;
  if (t < 4) scal[t] = 0.f;
  __syncthreads();
  int c3;
#pragma unroll
  for (int g = 0; g < 4; ++g) {
    int c = cls[t * 4 + g];
    atomicAdd(&cnt_s[g * 8 + c], 1);
    if (g == 3) c3 = c;
  }
  int pos = atomicAdd(&cc_s[c3], 1);
  order[c3 * 128 + pos] = t;
  red[t] = minv[t * 4 + 0] + minv[t * 4 + 1] + minv[t * 4 + 2] + minv[t * 4 + 3];
  __syncthreads();
  for (int o = 64; o > 0; o >>= 1) { if (t < o) red[t] += red[t + o]; __syncthreads(); }
  if (t == 0) scal[0] = red[0];
  if (t < 32) counts[t] = cnt_s[t];
  if (t < 8) ccnt[t] = cc_s[t];
}

// ---------------- K2: std_loss partials + M matrix (112 x 1024) ----------------
__global__ __launch_bounds__(256) void k_stats(
    const float* __restrict__ p2, const float* __restrict__ p3,
    const float* __restrict__ p4, const float* __restrict__ p5,
    const int* __restrict__ counts, float* __restrict__ M, float* __restrict__ scal)
{
  int idx = blockIdx.x * 256 + threadIdx.x;   // 56*256 = 14336 = NS*ND
  int s = idx >> 10, d = idx & 1023;
  int g, k; s_decomp(s, g, k);
  const float* pp = grp_ptr(g, p2, p3, p4, p5);
  int kg = grp_k(g);
  float vc[8], nc[8];
  float sum = 0.f, sumsq = 0.f;
#pragma unroll
  for (int c = 0; c < 8; ++c) {
    float v = pp[((size_t)(c * kg + k)) * ND + d];
    float n = (float)counts[g * 8 + c];
    vc[c] = v; nc[c] = n;
    sum += n * v; sumsq += n * v * v;
  }
  float mean = sum * (1.f / 128.f);
  float var = (sumsq - 128.f * mean * mean) * (1.f / 127.f);
  float sd = sqrtf(var + 1e-4f);
#pragma unroll
  for (int c = 0; c < 8; ++c)
    M[((size_t)(s * 8 + c)) * ND + d] = sqrtf(nc[c] * (1.f / 1791.f)) * (vc[c] - mean);
  float part = fmaxf(1.f - sd, 0.f);
  __shared__ float red[256];
  red[threadIdx.x] = part; __syncthreads();
  for (int o = 128; o > 0; o >>= 1) { if (threadIdx.x < o) red[threadIdx.x] += red[threadIdx.x + o]; __syncthreads(); }
  if (threadIdx.x == 0) atomicAdd(&scal[1], red[0]);
}

// ---------------- K3: blocks 0..111 gram rows; blocks 112..119 diag (float4 dots) ----------------
__global__ __launch_bounds__(128) void k_gramdiag(const float* __restrict__ M, float* __restrict__ scal)
{
  __shared__ __align__(16) float mi[ND];
  __shared__ float red[128];
  int bid = blockIdx.x, t = threadIdx.x;
  if (bid < 112) {
    float4* mi4 = (float4*)mi;
    const float4* src4 = (const float4*)(M + (size_t)bid * ND);
    for (int d = t; d < 256; d += 128) mi4[d] = src4[d];
    __syncthreads();
    float p = 0.f;
    if (t < 112) {
      const float4* mj4 = (const float4*)(M + (size_t)t * ND);
      float acc = 0.f;
#pragma unroll 8
      for (int d = 0; d < 256; ++d) {
        float4 a = mi4[d], b = mj4[d];
        acc += a.x * b.x + a.y * b.y + a.z * b.z + a.w * b.w;
      }
      p = acc * acc;
    }
    red[t] = p; __syncthreads();
    for (int o = 64; o > 0; o >>= 1) { if (t < o) red[t] += red[t + o]; __syncthreads(); }
    if (t == 0) atomicAdd(&scal[2], red[0]);
  } else {
    int d = (bid - 112) * 128 + t;
    float tsum = 0.f;
    for (int r = 0; r < 112; ++r) { float v = M[(size_t)r * ND + d]; tsum += v * v; }
    red[t] = tsum * tsum; __syncthreads();
    for (int o = 64; o > 0; o >>= 1) { if (t < o) red[t] += red[t + o]; __syncthreads(); }
    if (t == 0) atomicAdd(&scal[3], red[0]);
  }
}

// ---------------- K6: qkv, LDS-free streaming. 128 thr (2 waves x 16 cols), grid (96,8) ----------------
__global__ __launch_bounds__(128) void k_qkv_mfma(
    const unsigned short* __restrict__ hbf2, const float* __restrict__ w_qkv,
    const float* __restrict__ b_qkv, unsigned short* __restrict__ qkv_bf)
{
  int c = blockIdx.y;
  int t = threadIdx.x, lane = t & 63, wv = t >> 6;
  int r16 = lane & 15, q = lane >> 4;
  int col = blockIdx.x * 32 + wv * 16 + r16;
  const float* Wp = w_qkv + ((size_t)c * 3072 + col) * ND + q * 8;
  const unsigned short* Hp = hbf2 + (size_t)c * 114688 + lane * 8;
  f32x4 acc[7] = {};
#pragma unroll 2
  for (int kb = 0; kb < 32; ++kb) {
    float4 w0 = *(const float4*)(Wp + kb * 32);
    float4 w1 = *(const float4*)(Wp + kb * 32 + 4);
    bf16x8 bv = pack_bv(w0, w1);
    const unsigned short* hk = Hp + kb * 3584;   // 7*512
#pragma unroll
    for (int m = 0; m < 7; ++m) {
      bf16x8 av = *(const bf16x8*)(hk + m * 512);
      acc[m] = __builtin_amdgcn_mfma_f32_16x16x32_bf16(av, bv, acc[m], 0, 0, 0);
    }
  }
  float bq = b_qkv[(size_t)c * 3072 + col];
  int rbase = q * 4;
#pragma unroll
  for (int m = 0; m < 7; ++m)
#pragma unroll
    for (int r = 0; r < 4; ++r)
      qkv_bf[((size_t)c * 112 + m * 16 + rbase + r) * 3072 + col] = f2bf(acc[m][r] + bq);
}

// ---------------- K7: attention per (head, sample); writes obf2 in frag layout ----------------
// obf2 elem index: b*14336 + kblk*448 + s*32 + q*8 + e   (holds O[s][k=kblk*32+q*8+e])
__global__ __launch_bounds__(256) void k_attn(
    const unsigned short* __restrict__ qkv_bf, const int* __restrict__ cls,
    const int* __restrict__ rows_g, unsigned short* __restrict__ obf2)
{
  __shared__ __align__(16) float qs[NS * NDH], ks2[NS * NDH], vs[NS * NDH];
  __shared__ float sc[NS * NS];
  __shared__ int rg[NS];
  int h = blockIdx.x, b = blockIdx.y, t = threadIdx.x;
  if (t < NS) rg[t] = rows_g[b * NS + t];
  __syncthreads();
  int cp = cls[b * 4 + 3];
  const float scale = 0.08838834764831843f;  // 128^-0.5
  for (int i = t; i < NS * 64; i += 256) {   // 896 ushort2 pairs
    int s = i >> 6, e2 = (i & 63) * 2;
    size_t base = ((size_t)cp * 112 + rg[s]) * 3072 + h * NDH + e2;
    unsigned int uq = *(const unsigned int*)&qkv_bf[base];
    unsigned int uk = *(const unsigned int*)&qkv_bf[base + 1024];
    unsigned int uv = *(const unsigned int*)&qkv_bf[base + 2048];
    qs[s * NDH + e2]      = bf2f((unsigned short)uq) * scale;
    qs[s * NDH + e2 + 1]  = bf2f((unsigned short)(uq >> 16)) * scale;
    ks2[s * NDH + e2]     = bf2f((unsigned short)uk);
    ks2[s * NDH + e2 + 1] = bf2f((unsigned short)(uk >> 16));
    vs[s * NDH + e2]      = bf2f((unsigned short)uv);
    vs[s * NDH + e2 + 1]  = bf2f((unsigned short)(uv >> 16));
  }
  __syncthreads();
  if (t < NS * NS) {
    int si = t / NS, sj = t - (t / NS) * NS;
    const float4* qa = (const float4*)&qs[si * NDH];
    const float4* kb = (const float4*)&ks2[sj * NDH];
    float acc = 0.f;
#pragma unroll 8
    for (int e4 = 0; e4 < 32; ++e4) {
      float4 a = qa[e4], k4 = kb[e4];
      acc += a.x * k4.x + a.y * k4.y + a.z * k4.z + a.w * k4.w;
    }
    sc[t] = acc;
  }
  __syncthreads();
  if (t < NS) {
    float m = -1e30f;
    for (int j = 0; j < NS; ++j) m = fmaxf(m, sc[t * NS + j]);
    float e_[NS]; float sum = 0.f;
    for (int j = 0; j < NS; ++j) { float e = expf(sc[t * NS + j] - m); e_[j] = e; sum += e; }
    float inv = 1.f / sum;
    for (int j = 0; j < NS; ++j) sc[t * NS + j] = e_[j] * inv;
  }
  __syncthreads();
  for (int i = t; i < NS * 32; i += 256) {   // 448 float4 outputs
    int s = i >> 5, e4 = i & 31;
    float4 a = {0.f, 0.f, 0.f, 0.f};
#pragma unroll
    for (int j = 0; j < NS; ++j) {
      float w = sc[s * NS + j];
      float4 v4 = ((const float4*)&vs[j * NDH])[e4];
      a.x += w * v4.x; a.y += w * v4.y; a.z += w * v4.z; a.w += w * v4.w;
    }
    int d = h * NDH + e4 * 4;                 // feature index, multiple of 4
    int kblk = d >> 5, qq = (d >> 3) & 3, e0 = d & 7;   // e0 in {0,4}
    ushort4 u; u.x = f2bf(a.x); u.y = f2bf(a.y); u.z = f2bf(a.z); u.w = f2bf(a.w);
    *(ushort4*)&obf2[(size_t)b * 14336 + kblk * 448 + s * 32 + qq * 8 + e0] = u;
  }
}

// ---------------- K8: proj, LDS-free streaming, chunk=16 (M=224). 256 thr, grid (16,64) ----------------
__global__ __launch_bounds__(256) void k_proj_mfma(
    const unsigned short* __restrict__ obf2, const int* __restrict__ order,
    const int* __restrict__ ccnt, const int* __restrict__ rows_g,
    const float* __restrict__ w_proj, const float* __restrict__ b_proj,
    const float* __restrict__ pall, float* __restrict__ att)
{
  int c = blockIdx.y >> 3, ch = blockIdx.y & 7;
  int cnt = ccnt[c];
  int nb = cnt - ch * 16;
  if (nb <= 0) return;
  if (nb > 16) nb = 16;
  __shared__ int sid_s[16];
  int t = threadIdx.x, lane = t & 63, wv = t >> 6;
  if (t < 16) sid_s[t] = order[c * 128 + ch * 16 + ((t < nb) ? t : 0)];
  __syncthreads();
  int r16 = lane & 15, q = lane >> 4;
  int col = blockIdx.x * 64 + wv * 16 + r16;
  const float* Wp = w_proj + ((size_t)c * ND + col) * ND + q * 8;
  const unsigned short* ap[14];
#pragma unroll
  for (int m = 0; m < 14; ++m) {
    int row = m * 16 + r16;
    int si = row / 14, s = row - si * 14;
    ap[m] = obf2 + (size_t)sid_s[si] * 14336 + s * 32 + q * 8;
  }
  f32x4 acc[14] = {};
#pragma unroll 2
  for (int kb = 0; kb < 32; ++kb) {
    float4 w0 = *(const float4*)(Wp + kb * 32);
    float4 w1 = *(const float4*)(Wp + kb * 32 + 4);
    bf16x8 bv = pack_bv(w0, w1);
    int ko = kb * 448;
#pragma unroll
    for (int m = 0; m < 14; ++m) {
      bf16x8 av = *(const bf16x8*)(ap[m] + ko);
      acc[m] = __builtin_amdgcn_mfma_f32_16x16x32_bf16(av, bv, acc[m], 0, 0, 0);
    }
  }
  float bp = b_proj[(size_t)c * ND + col];
  int rbase = q * 4;
#pragma unroll
  for (int m = 0; m < 14; ++m)
#pragma unroll
    for (int r = 0; r < 4; ++r) {
      int row = m * 16 + rbase + r;
      int si = row / 14, s = row - si * 14;
      if (si < nb) {
        int b = sid_s[si];
        float res = pall[(size_t)rows_g[b * NS + s] * ND + col];
        att[((size_t)b * NS + s) * ND + col] = acc[m][r] + bp + res;
      }
    }
}

// ---------------- K9: single-pass normalize+pool+logits from LDS tile; write vcr ----------------
__global__ __launch_bounds__(256) void k_final(
    const float* __restrict__ att, const float* __restrict__ w_cls,
    const float* __restrict__ b_cls, const float* __restrict__ scal,
    float* __restrict__ out)
{
  int b = blockIdx.x, t = threadIdx.x;
  __shared__ __align__(16) float as[NS * ND];   // 56 KB
  __shared__ float wred[NS][4];
  __shared__ float inv[NS];
  __shared__ __align__(16) float pooled[ND];
  int lane = t & 63, w = t >> 6;
#pragma unroll
  for (int s = 0; s < NS; ++s) {
    float4 v = ((const float4*)(att + ((size_t)b * NS + s) * ND))[t];
    ((float4*)&as[s * ND])[t] = v;
    float p = v.x * v.x + v.y * v.y + v.z * v.z + v.w * v.w;
#pragma unroll
    for (int o = 32; o > 0; o >>= 1) p += __shfl_xor(p, o, 64);
    if (lane == 0) wred[s][w] = p;
  }
  __syncthreads();
  if (t < NS) {
    float s2 = wred[t][0] + wred[t][1] + wred[t][2] + wred[t][3];
    inv[t] = 1.f / fmaxf(sqrtf(s2), 1e-12f);
  }
  __syncthreads();
  float4 pa = {0.f, 0.f, 0.f, 0.f};
#pragma unroll
  for (int s = 0; s < NS; ++s) {
    float iv = inv[s];
    float4 v = ((const float4*)&as[s * ND])[t];
    pa.x += iv * v.x; pa.y += iv * v.y; pa.z += iv * v.z; pa.w += iv * v.w;
  }
  const float k14 = 1.f / 14.f;
  pa.x *= k14; pa.y *= k14; pa.z *= k14; pa.w *= k14;
  ((float4*)pooled)[t] = pa;
  __syncthreads();
  int c = t >> 5, l = t & 31;
  float acc = 0.f;
#pragma unroll
  for (int k = 0; k < 8; ++k) {
    int i4 = l + k * 32;
    float4 p4 = ((const float4*)pooled)[i4];
    float4 wc = ((const float4*)(w_cls + (size_t)c * ND))[i4];
    acc += p4.x * wc.x + p4.y * wc.y + p4.z * wc.z + p4.w * wc.w;
  }
  for (int o = 16; o > 0; o >>= 1) acc += __shfl_down(acc, o, 32);
  if (l == 0) out[b * 8 + c] = acc + b_cls[c];
  if (b == 0 && t == 0) {
    float repr = scal[0] * (1.f / (128.f * 4.f * 1024.f));
    float stdl = scal[1] * (1.f / 14336.f);
    float covl = (scal[2] - scal[3]) * (1.f / 1024.f);
    out[1024] = 25.f * repr + 25.f * stdl + covl;
  }
}

extern "C" void kernel_launch(void* const* d_in, const int* in_sizes, int n_in,
                              void* d_out, int out_size, void* d_ws, size_t ws_size,
                              hipStream_t stream) {
  const float* x      = (const float*)d_in[0];
  const float* p2     = (const float*)d_in[1];
  const float* p3     = (const float*)d_in[2];
  const float* p4     = (const float*)d_in[3];
  const float* p5     = (const float*)d_in[4];
  const float* ln_g   = (const float*)d_in[5];
  const float* ln_b   = (const float*)d_in[6];
  const float* w_qkv  = (const float*)d_in[7];
  const float* b_qkv  = (const float*)d_in[8];
  const float* w_proj = (const float*)d_in[9];
  const float* b_proj = (const float*)d_in[10];
  const float* w_cls  = (const float*)d_in[11];
  const float* b_cls  = (const float*)d_in[12];
  float* out = (float*)d_out;
  char* ws = (char*)d_ws;

  float* scal   = (float*)(ws + 0);            // [0]=repr [1]=std [2]=fro [3]=diagsq
  int*   counts = (int*)(ws + 64);             // [4][8]
  int*   ccnt   = (int*)(ws + 192);            // [8]
  int*   cls    = (int*)(ws + 256);            // [128][4]
  int*   rows_g = (int*)(ws + 2304);           // [128][14]
  int*   order  = (int*)(ws + 9472);           // [8][128]
  float* minv   = (float*)(ws + 13568);        // [128][4]
  float* pall   = (float*)(ws + 16384);        // 112*1024 f32          -> 475,136
  unsigned short* hbf2 = (unsigned short*)(ws + 475136);   // 8*114688 bf16 frag -> 2,310,144
  unsigned short* qkvb = (unsigned short*)(ws + 2310144);  // 8*112*3072 bf16    -> 9,191,424
  unsigned short* obf2 = (unsigned short*)(ws + 9191424);  // 128*14336 bf16 frag-> 12,861,440
  float* att    = (float*)(ws + 12861440);     // 128*14*1024 f32       -> 20,201,472
  float* M      = (float*)(ws + 20201472);     // 112*1024 f32          -> 20,660,224

  k_assign_ln<<<240, 256, 0, stream>>>(x, p2, p3, p4, p5, ln_g, ln_b, hbf2, pall, cls, rows_g, minv);
  k_qkv_mfma<<<dim3(96, 8), 128, 0, stream>>>(hbf2, w_qkv, b_qkv, qkvb);
  k_prep<<<1, 128, 0, stream>>>(cls, minv, counts, ccnt, order, scal);
  k_stats<<<56, 256, 0, stream>>>(p2, p3, p4, p5, counts, M, scal);
  k_gramdiag<<<120, 128, 0, stream>>>(M, scal);
  k_attn<<<dim3(8, 128), 256, 0, stream>>>(qkvb, cls, rows_g, obf2);
  k_proj_mfma<<<dim3(16, 64), 256, 0, stream>>>(obf2, order, ccnt, rows_g, w_proj, b_proj, pall, att);
  k_final<<<128, 256, 0, stream>>>(att, w_cls, b_cls, scal, out);
}